// Round 14
// baseline (272.219 us; speedup 1.0000x reference)
//
#include <hip/hip_runtime.h>

#define NN     1024
#define IN_D   256
#define OUT_D  256
#define RPB    4                       // rows per block
#define KSPLIT 4                       // K-slices
#define NPAIRS 128                     // total i-pairs
#define PPK    (NPAIRS / KSPLIT)       // 32 i-pairs per K-slice
#define IPK    (IN_D / KSPLIT)         // 64 i per K-slice

typedef float v2f __attribute__((ext_vector_type(2)));
typedef float v4f __attribute__((ext_vector_type(4)));

#define WLR_BYTES   (sizeof(v4f) * NPAIRS * OUT_D)        // 512 KB
#define PART_BYTES  (sizeof(v2f) * KSPLIT * NN * OUT_D)   // 8 MB
#define SINK_FLOATS (KSPLIT * (NN / RPB) * 256)
#define TOT_BYTES   (WLR_BYTES + PART_BYTES + SINK_FLOATS * sizeof(float))

__global__ __launch_bounds__(256) void fz_prep(
    const float* __restrict__ wb, const float* __restrict__ wa,
    const float* __restrict__ wc, v4f* __restrict__ wlr2) {
    int t  = blockIdx.x * 256 + threadIdx.x;   // 0 .. NPAIRS*OUT-1
    int pr = t >> 8;
    int o  = t & (OUT_D - 1);
    int i0 = (2 * pr) * OUT_D + o;
    int i1 = i0 + OUT_D;
    v4f w;
    w.x = wb[i0] - fmaxf(wa[i0], 0.0f);        // wl(2p)
    w.y = wb[i0] + fmaxf(wc[i0], 0.0f);        // wr(2p)
    w.z = wb[i1] - fmaxf(wa[i1], 0.0f);        // wl(2p+1)
    w.w = wb[i1] + fmaxf(wc[i1], 0.0f);        // wr(2p+1)
    wlr2[t] = w;
}

// h = {a0,b0,a1,b1}; WL = {wl0,wl1}; WR = {wr0,wr1}
// invariants: b>=a (hr>=hl), wr>0 => min4 = min3(awl,bwl,awr), max4 = max3(awl,bwl,bwr)
__device__ __forceinline__ void pair_math(v4f h, v2f WL, v2f WR, v2f& aL, v2f& aR) {
    v2f A; A.x = h.x; A.y = h.z;               // hl at i0,i1 (register select)
    v2f B; B.x = h.y; B.y = h.w;               // hr at i0,i1
    v2f X  = A * WL;                           // v_pk_mul_f32
    v2f Y  = B * WL;
    v2f ZL = A * WR;
    v2f ZR = B * WR;
    v2f mn, mx;
    mn.x = fminf(fminf(X.x, Y.x), ZL.x);       // v_min3_f32
    mn.y = fminf(fminf(X.y, Y.y), ZL.y);
    mx.x = fmaxf(fmaxf(X.x, Y.x), ZR.x);       // v_max3_f32
    mx.y = fmaxf(fmaxf(X.y, Y.y), ZR.y);
    aL += mn;                                  // v_pk_add_f32
    aR += mx;
}

template <int REPS, bool PROBE>
__global__ __launch_bounds__(256) void fz_m(
    const float* __restrict__ hl, const float* __restrict__ hr,
    const v4f* __restrict__ wlr2, v2f* __restrict__ part,
    float* __restrict__ sink) {
    __shared__ __align__(16) v2f ab[RPB][IPK]; // 2 KB {hl,hr} for this K-slice

    const int tid = threadIdx.x;
    const int o   = tid;
    const int nb  = blockIdx.x;
    const int k   = blockIdx.y;
    const int n0  = nb * RPB;

    // stage: thread t -> (row, il); coalesced 64-wide per row
    {
        int row = tid >> 6, il = tid & 63;
        v2f v;
        v.x = hl[(n0 + row) * IN_D + k * IPK + il];
        v.y = hr[(n0 + row) * IN_D + k * IPK + il];
        ab[row][il] = v;
    }
    __syncthreads();

    int jit = 0;
    if (REPS > 1) asm volatile("v_mov_b32 %0, 0" : "=v"(jit));   // opaque 0

    v2f aL0 = (v2f)(0.0f), aR0 = (v2f)(0.0f), aL1 = (v2f)(0.0f), aR1 = (v2f)(0.0f);
    v2f aL2 = (v2f)(0.0f), aR2 = (v2f)(0.0f), aL3 = (v2f)(0.0f), aR3 = (v2f)(0.0f);

    const v4f* wbase = wlr2 + (size_t)(k * PPK) * OUT_D + o;

#pragma unroll 1
    for (int rep = 0; rep < REPS; ++rep) {
        if (REPS > 1) __syncthreads();         // defeat cross-rep LDS CSE
        const v4f* wq = wbase + jit * rep;     // runtime 0

        auto PAIR = [&](int jj, v4f w) {
            v2f WL; WL.x = w.x; WL.y = w.z;
            v2f WR; WR.x = w.y; WR.y = w.w;
            v4f h0 = *reinterpret_cast<const v4f*>(&ab[0][2 * jj]);  // b128 bcast
            v4f h1 = *reinterpret_cast<const v4f*>(&ab[1][2 * jj]);
            v4f h2 = *reinterpret_cast<const v4f*>(&ab[2][2 * jj]);
            v4f h3 = *reinterpret_cast<const v4f*>(&ab[3][2 * jj]);
            pair_math(h0, WL, WR, aL0, aR0);
            pair_math(h1, WL, WR, aL1, aR1);
            pair_math(h2, WL, WR, aL2, aR2);
            pair_math(h3, WL, WR, aL3, aR3);
        };

        // depth-4 named-register W rotation, fully static
        v4f w0 = wq[0];
        v4f w1 = wq[(size_t)1 * OUT_D];
        v4f w2 = wq[(size_t)2 * OUT_D];
        v4f w3 = wq[(size_t)3 * OUT_D];
#pragma unroll
        for (int j4 = 0; j4 < PPK; j4 += 4) {
            PAIR(j4 + 0, w0); if (j4 + 4 < PPK) w0 = wq[(size_t)(j4 + 4) * OUT_D];
            PAIR(j4 + 1, w1); if (j4 + 5 < PPK) w1 = wq[(size_t)(j4 + 5) * OUT_D];
            PAIR(j4 + 2, w2); if (j4 + 6 < PPK) w2 = wq[(size_t)(j4 + 6) * OUT_D];
            PAIR(j4 + 3, w3); if (j4 + 7 < PPK) w3 = wq[(size_t)(j4 + 7) * OUT_D];
        }
    }

    if (!PROBE) {
        // horizontal sum over the 2 i-lanes -> {L,R} per row; coalesced 8B
        size_t base = ((size_t)k * NN + n0) * OUT_D + o;
        v2f p;
        p.x = aL0.x + aL0.y; p.y = aR0.x + aR0.y; part[base]             = p;
        p.x = aL1.x + aL1.y; p.y = aR1.x + aR1.y; part[base + OUT_D]     = p;
        p.x = aL2.x + aL2.y; p.y = aR2.x + aR2.y; part[base + 2 * OUT_D] = p;
        p.x = aL3.x + aL3.y; p.y = aR3.x + aR3.y; part[base + 3 * OUT_D] = p;
    } else {
        float s = aL0.x + aL0.y + aR0.x + aR0.y + aL1.x + aL1.y + aR1.x + aR1.y
                + aL2.x + aL2.y + aR2.x + aR2.y + aL3.x + aL3.y + aR3.x + aR3.y;
        sink[((size_t)k * (NN / RPB) + nb) * 256 + tid] = s;
    }
}

__global__ __launch_bounds__(256) void fz_reduce(
    const v2f* __restrict__ part,
    const float* __restrict__ bb, const float* __restrict__ ba,
    const float* __restrict__ bc, float* __restrict__ out) {
    int idx = blockIdx.x * 256 + threadIdx.x;  // 0 .. NN*OUT-1
    int o   = idx & (OUT_D - 1);
    v2f s = part[idx];
    s += part[(size_t)1 * NN * OUT_D + idx];
    s += part[(size_t)2 * NN * OUT_D + idx];
    s += part[(size_t)3 * NN * OUT_D + idx];
    float bl = bb[o] - fmaxf(ba[o], 0.0f);
    float br = bb[o] + fmaxf(bc[o], 0.0f);
    out[idx]                      = s.x + bl;
    out[(size_t)NN * OUT_D + idx] = s.y + br;
}

// correctness-only fallback if ws too small
__global__ __launch_bounds__(256) void fz_fallback(
    const float* __restrict__ hl, const float* __restrict__ hr,
    const float* __restrict__ wb, const float* __restrict__ wa,
    const float* __restrict__ wc,
    const float* __restrict__ bb, const float* __restrict__ ba,
    const float* __restrict__ bc, float* __restrict__ out) {
    const int o  = threadIdx.x;
    const int n  = blockIdx.x;
    float aL = 0.0f, aR = 0.0f;
    for (int i = 0; i < IN_D; ++i) {
        int wi = i * OUT_D + o;
        float wl = wb[wi] - fmaxf(wa[wi], 0.0f);
        float wr = wb[wi] + fmaxf(wc[wi], 0.0f);
        float a = hl[n * IN_D + i], b = hr[n * IN_D + i];
        float x = a * wl, y = b * wl, zl = a * wr, zr = b * wr;
        aL += fminf(fminf(x, y), zl);
        aR += fmaxf(fmaxf(x, y), zr);
    }
    out[(size_t)n * OUT_D + o]                      = aL + bb[o] - fmaxf(ba[o], 0.0f);
    out[(size_t)NN * OUT_D + (size_t)n * OUT_D + o] = aR + bb[o] + fmaxf(bc[o], 0.0f);
}

extern "C" void kernel_launch(void* const* d_in, const int* in_sizes, int n_in,
                              void* d_out, int out_size, void* d_ws, size_t ws_size,
                              hipStream_t stream) {
    const float* hl = (const float*)d_in[0];
    const float* hr = (const float*)d_in[1];
    const float* wb = (const float*)d_in[2];
    const float* wa = (const float*)d_in[3];
    const float* wc = (const float*)d_in[4];
    const float* bb = (const float*)d_in[5];
    const float* ba = (const float*)d_in[6];
    const float* bc = (const float*)d_in[7];
    float* out = (float*)d_out;

    if (ws_size >= TOT_BYTES) {
        v4f*   wlr2 = (v4f*)d_ws;
        v2f*   part = (v2f*)((char*)d_ws + WLR_BYTES);
        float* sink = (float*)((char*)d_ws + WLR_BYTES + PART_BYTES);
        fz_prep<<<(NPAIRS * OUT_D) / 256, 256, 0, stream>>>(wb, wa, wc, wlr2);
        fz_m<16, true><<<dim3(NN / RPB, KSPLIT), 256, 0, stream>>>(
            hl, hr, wlr2, nullptr, sink);                         // REP-16 probe
        fz_m<1, false><<<dim3(NN / RPB, KSPLIT), 256, 0, stream>>>(
            hl, hr, wlr2, part, nullptr);
        fz_reduce<<<(NN * OUT_D) / 256, 256, 0, stream>>>(part, bb, ba, bc, out);
    } else {
        fz_fallback<<<NN, 256, 0, stream>>>(hl, hr, wb, wa, wc, bb, ba, bc, out);
    }
}

// Round 15
// 24.704 us; speedup vs baseline: 11.0192x; 11.0192x over previous
//
#include <hip/hip_runtime.h>

#define NN    1024
#define IN_D  256
#define OUT_D 256
#define RPB   4                   // rows per block; grid = 256 = 1 block/CU
#define NG    4                   // K-groups (1024 thr = 256 o x 4 g)
#define PPG   32                  // i-pairs per group (NG*PPG = 128 pairs = 256 i)
#define GRP   4                   // pairs per f16-accumulate group (flush to f32 after)

typedef float v2f __attribute__((ext_vector_type(2)));
typedef _Float16 h2 __attribute__((ext_vector_type(2)));
typedef _Float16 h4 __attribute__((ext_vector_type(4)));

#define WPK_BYTES (sizeof(h4) * 128 * OUT_D)     // 256 KB

// wpk[pair*256+o] = {wl(2p,o), wl(2p+1,o), wr(2p,o), wr(2p+1,o)} as f16x4
__global__ __launch_bounds__(256) void fz_prep(
    const float* __restrict__ wb, const float* __restrict__ wa,
    const float* __restrict__ wc, h4* __restrict__ wpk) {
    int t  = blockIdx.x * 256 + threadIdx.x;     // 0 .. 128*256-1
    int pr = t >> 8;
    int o  = t & (OUT_D - 1);
    int i0 = (2 * pr) * OUT_D + o;
    int i1 = i0 + OUT_D;
    float wl0 = wb[i0] - fmaxf(wa[i0], 0.0f);
    float wr0 = wb[i0] + fmaxf(wc[i0], 0.0f);
    float wl1 = wb[i1] - fmaxf(wa[i1], 0.0f);
    float wr1 = wb[i1] + fmaxf(wc[i1], 0.0f);
    h4 w;
    w.x = (_Float16)wl0; w.y = (_Float16)wl1;
    w.z = (_Float16)wr0; w.w = (_Float16)wr1;
    wpk[t] = w;
}

__global__ __launch_bounds__(1024) void fz_main(
    const float* __restrict__ hl, const float* __restrict__ hr,
    const h4* __restrict__ wpk,
    const float* __restrict__ bb, const float* __restrict__ ba,
    const float* __restrict__ bc, float* __restrict__ out) {
    __shared__ __align__(8) h4  hp[RPB][128];        // 4 KB {a0,a1,b0,b1} per (row,pair)
    __shared__ __align__(8) v2f pl[NG][RPB][OUT_D];  // 32 KB partials {L,R}

    const int tid = threadIdx.x;
    const int o   = tid & (OUT_D - 1);
    const int g   = tid >> 8;                    // 0..3
    const int n0  = blockIdx.x * RPB;

    // ---- stage h rows as f16 quads: 512 items, threads 0..511, coalesced ----
    if (tid < RPB * 128) {
        int row = tid >> 7;                      // 0..3
        int p   = tid & 127;
        float2 va = reinterpret_cast<const float2*>(hl)[(size_t)(n0 + row) * 128 + p];
        float2 vb = reinterpret_cast<const float2*>(hr)[(size_t)(n0 + row) * 128 + p];
        h4 h;
        h.x = (_Float16)va.x; h.y = (_Float16)va.y;   // a(2p), a(2p+1)
        h.z = (_Float16)vb.x; h.w = (_Float16)vb.y;   // b(2p), b(2p+1)
        hp[row][p] = h;
    }
    __syncthreads();

    const int j0 = g * PPG;
    const h4* wq = wpk + (size_t)j0 * OUT_D + o;

    float fL0 = 0.0f, fR0 = 0.0f, fL1 = 0.0f, fR1 = 0.0f;
    float fL2 = 0.0f, fR2 = 0.0f, fL3 = 0.0f, fR3 = 0.0f;

#pragma unroll
    for (int gg = 0; gg < PPG / GRP; ++gg) {     // 8 groups of 4 pairs
        h2 aL0 = (h2)(_Float16)0, aR0 = (h2)(_Float16)0;
        h2 aL1 = (h2)(_Float16)0, aR1 = (h2)(_Float16)0;
        h2 aL2 = (h2)(_Float16)0, aR2 = (h2)(_Float16)0;
        h2 aL3 = (h2)(_Float16)0, aR3 = (h2)(_Float16)0;
#pragma unroll
        for (int j = 0; j < GRP; ++j) {
            const int jp = gg * GRP + j;
            h4 w  = wq[(size_t)jp * OUT_D];                       // dwordx2, coalesced
            h2 WL = __builtin_shufflevector(w, w, 0, 1);
            h2 WR = __builtin_shufflevector(w, w, 2, 3);
            // invariants: b>=a (hr>=hl), wr>0:
            //   min4 = min3(a*wl, b*wl, a*wr); max4 = max3(a*wl, b*wl, b*wr)
#define FZ_ROW(r, aL, aR)                                                   \
            {                                                               \
                h4 h = hp[r][j0 + jp];              /* ds_read_b64 bcast */ \
                h2 A = __builtin_shufflevector(h, h, 0, 1);                 \
                h2 B = __builtin_shufflevector(h, h, 2, 3);                 \
                h2 X = A * WL, Y = B * WL, ZL = A * WR, ZR = B * WR;        \
                h2 mn = __builtin_elementwise_min(                          \
                            __builtin_elementwise_min(X, Y), ZL);           \
                h2 mx = __builtin_elementwise_max(                          \
                            __builtin_elementwise_max(X, Y), ZR);           \
                aL += mn;                            /* v_pk_add_f16 */     \
                aR += mx;                                                   \
            }
            FZ_ROW(0, aL0, aR0)
            FZ_ROW(1, aL1, aR1)
            FZ_ROW(2, aL2, aR2)
            FZ_ROW(3, aL3, aR3)
#undef FZ_ROW
        }
        // flush f16 group accumulators to f32 (error containment)
        fL0 += (float)aL0.x + (float)aL0.y;  fR0 += (float)aR0.x + (float)aR0.y;
        fL1 += (float)aL1.x + (float)aL1.y;  fR1 += (float)aR1.x + (float)aR1.y;
        fL2 += (float)aL2.x + (float)aL2.y;  fR2 += (float)aR2.x + (float)aR2.y;
        fL3 += (float)aL3.x + (float)aL3.y;  fR3 += (float)aR3.x + (float)aR3.y;
    }

    {
        v2f p;
        p.x = fL0; p.y = fR0; pl[g][0][o] = p;
        p.x = fL1; p.y = fR1; pl[g][1][o] = p;
        p.x = fL2; p.y = fR2; pl[g][2][o] = p;
        p.x = fL3; p.y = fR3; pl[g][3][o] = p;
    }
    __syncthreads();

    // ---- epilogue: 1024 threads x 2 outputs = 2 sides x 4 rows x 256 o ----
    {
        int side = tid >> 9;                     // 0 = L, 1 = R
        int r0   = (tid >> 8) & 1;               // rows r0 and r0+2
        int oo   = tid & (OUT_D - 1);
        float bias = side ? (bb[oo] + fmaxf(bc[oo], 0.0f))
                          : (bb[oo] - fmaxf(ba[oo], 0.0f));
#pragma unroll
        for (int rr = 0; rr < 2; ++rr) {
            int r = r0 + 2 * rr;
            v2f s = pl[0][r][oo];
            s += pl[1][r][oo];
            s += pl[2][r][oo];
            s += pl[3][r][oo];
            float v = side ? s.y : s.x;
            out[(size_t)side * NN * OUT_D + (size_t)(n0 + r) * OUT_D + oo] = v + bias;
        }
    }
}

// correctness-only fallback if ws too small (not expected to run)
__global__ __launch_bounds__(256) void fz_fallback(
    const float* __restrict__ hl, const float* __restrict__ hr,
    const float* __restrict__ wb, const float* __restrict__ wa,
    const float* __restrict__ wc,
    const float* __restrict__ bb, const float* __restrict__ ba,
    const float* __restrict__ bc, float* __restrict__ out) {
    const int o = threadIdx.x;
    const int n = blockIdx.x;
    float aL = 0.0f, aR = 0.0f;
    for (int i = 0; i < IN_D; ++i) {
        int wi = i * OUT_D + o;
        float wl = wb[wi] - fmaxf(wa[wi], 0.0f);
        float wr = wb[wi] + fmaxf(wc[wi], 0.0f);
        float a = hl[n * IN_D + i], b = hr[n * IN_D + i];
        float x = a * wl, y = b * wl, zl = a * wr, zr = b * wr;
        aL += fminf(fminf(x, y), zl);
        aR += fmaxf(fmaxf(x, y), zr);
    }
    out[(size_t)n * OUT_D + o]                      = aL + bb[o] - fmaxf(ba[o], 0.0f);
    out[(size_t)NN * OUT_D + (size_t)n * OUT_D + o] = aR + bb[o] + fmaxf(bc[o], 0.0f);
}

extern "C" void kernel_launch(void* const* d_in, const int* in_sizes, int n_in,
                              void* d_out, int out_size, void* d_ws, size_t ws_size,
                              hipStream_t stream) {
    const float* hl = (const float*)d_in[0];
    const float* hr = (const float*)d_in[1];
    const float* wb = (const float*)d_in[2];
    const float* wa = (const float*)d_in[3];
    const float* wc = (const float*)d_in[4];
    const float* bb = (const float*)d_in[5];
    const float* ba = (const float*)d_in[6];
    const float* bc = (const float*)d_in[7];
    float* out = (float*)d_out;

    if (ws_size >= WPK_BYTES) {
        h4* wpk = (h4*)d_ws;
        fz_prep<<<(128 * OUT_D) / 256, 256, 0, stream>>>(wb, wa, wc, wpk);
        fz_main<<<NN / RPB, 1024, 0, stream>>>(hl, hr, wpk, bb, ba, bc, out);
    } else {
        fz_fallback<<<NN, 256, 0, stream>>>(hl, hr, wb, wa, wc, bb, ba, bc, out);
    }
}